// Round 1
// baseline (1118.589 us; speedup 1.0000x reference)
//
#include <hip/hip_runtime.h>

#define N_USERS 100000
#define LATDIM 64
#define N_EDGES 1600000
#define N_LAYERS 3

// out[i] = src[i]
__global__ void k_copy(float* __restrict__ dst, const float* __restrict__ src, int n) {
    int i = blockIdx.x * blockDim.x + threadIdx.x;
    if (i < n) dst[i] = src[i];
}

// dst[i] = 0
__global__ void k_zero(float* __restrict__ dst, int n) {
    int i = blockIdx.x * blockDim.x + threadIdx.x;
    if (i < n) dst[i] = 0.0f;
}

// scatter: y[rows[e]*64 + d] += vals[e] * x[cols[e]*64 + d]
// one 64-lane group per edge; lane d handles dim d.
__global__ void k_spmm(const int* __restrict__ rows, const int* __restrict__ cols,
                       const float* __restrict__ vals, const float* __restrict__ x,
                       float* __restrict__ y, int n_edges) {
    long long t = (long long)blockIdx.x * blockDim.x + threadIdx.x;
    int e = (int)(t >> 6);
    int d = (int)(t & 63);
    if (e >= n_edges) return;
    int r = rows[e];
    int c = cols[e];
    float v = vals[e];
    atomicAdd(&y[(long long)r * LATDIM + d], v * x[(long long)c * LATDIM + d]);
}

// out[i] += src[i]
__global__ void k_accum(float* __restrict__ out, const float* __restrict__ src, int n) {
    int i = blockIdx.x * blockDim.x + threadIdx.x;
    if (i < n) out[i] += src[i];
}

extern "C" void kernel_launch(void* const* d_in, const int* in_sizes, int n_in,
                              void* d_out, int out_size, void* d_ws, size_t ws_size,
                              hipStream_t stream) {
    const int*   rows = (const int*)d_in[0];
    const int*   cols = (const int*)d_in[1];
    const float* vals = (const float*)d_in[2];
    const float* emb  = (const float*)d_in[3];
    float* out = (float*)d_out;

    const int n = N_USERS * LATDIM;            // 6.4M floats
    float* bufA = (float*)d_ws;                // 25.6 MB
    float* bufB = bufA + n;                    // 25.6 MB

    const int blk = 256;
    const int gN = (n + blk - 1) / blk;

    // out = emb
    k_copy<<<gN, blk, 0, stream>>>(out, emb, n);

    const float* cur = emb;
    float* bufs[2] = {bufA, bufB};
    for (int l = 0; l < N_LAYERS; ++l) {
        float* nxt = bufs[l & 1];
        k_zero<<<gN, blk, 0, stream>>>(nxt, n);
        long long threads = (long long)N_EDGES * 64;
        int gE = (int)((threads + blk - 1) / blk);
        k_spmm<<<gE, blk, 0, stream>>>(rows, cols, vals, cur, nxt, N_EDGES);
        k_accum<<<gN, blk, 0, stream>>>(out, nxt, n);
        cur = nxt;
    }
}

// Round 2
// 664.765 us; speedup vs baseline: 1.6827x; 1.6827x over previous
//
#include <hip/hip_runtime.h>

#define NU 100000
#define D  64
#define NE 1600000

#define SCAN_CHUNK 1024
#define NB_SCAN ((NU + SCAN_CHUNK - 1) / SCAN_CHUNK)   // 98

__global__ void k_zero_i(int* __restrict__ p, int n) {
    int i = blockIdx.x * blockDim.x + threadIdx.x;
    if (i < n) p[i] = 0;
}

__global__ void k_hist(const int* __restrict__ rows, int* __restrict__ counts) {
    int e = blockIdx.x * blockDim.x + threadIdx.x;
    if (e < NE) atomicAdd(&counts[rows[e]], 1);
}

// per-block exclusive scan; writes per-block-exclusive values + block totals
__global__ void k_scan1(const int* __restrict__ counts, int* __restrict__ excl,
                        int* __restrict__ blockSums) {
    __shared__ int s[SCAN_CHUNK];
    int t = threadIdx.x;
    int idx = blockIdx.x * SCAN_CHUNK + t;
    int v = (idx < NU) ? counts[idx] : 0;
    s[t] = v;
    __syncthreads();
    for (int off = 1; off < SCAN_CHUNK; off <<= 1) {
        int x = (t >= off) ? s[t - off] : 0;
        __syncthreads();
        s[t] += x;
        __syncthreads();
    }
    if (idx < NU) excl[idx] = s[t] - v;
    if (t == SCAN_CHUNK - 1) blockSums[blockIdx.x] = s[t];
}

// single-block exclusive scan of the 98 block totals (padded to 128)
__global__ void k_scan2(const int* __restrict__ blockSums, int* __restrict__ blockOff) {
    __shared__ int s[128];
    int t = threadIdx.x;
    int v = (t < NB_SCAN) ? blockSums[t] : 0;
    s[t] = v;
    __syncthreads();
    for (int off = 1; off < 128; off <<= 1) {
        int x = (t >= off) ? s[t - off] : 0;
        __syncthreads();
        s[t] += x;
        __syncthreads();
    }
    blockOff[t] = s[t] - v;
}

__global__ void k_scan3(int* __restrict__ rowptr, const int* __restrict__ blockOff,
                        int* __restrict__ cursor) {
    int idx = blockIdx.x * blockDim.x + threadIdx.x;
    if (idx < NU) {
        int v = rowptr[idx] + blockOff[idx / SCAN_CHUNK];
        rowptr[idx] = v;
        cursor[idx] = v;
    }
}

// counting-sort edges into CSR slots: (col, val) interleaved as int2
__global__ void k_scatter(const int* __restrict__ rows, const int* __restrict__ cols,
                          const float* __restrict__ vals, int* __restrict__ cursor,
                          int2* __restrict__ edges) {
    int e = blockIdx.x * blockDim.x + threadIdx.x;
    if (e < NE) {
        int r = rows[e];
        int pos = atomicAdd(&cursor[r], 1);
        edges[pos] = make_int2(cols[e], __float_as_int(vals[e]));
    }
}

// One 64-lane wave per output row; lane = latent dim.
// MODE 0: out = emb + acc; nxt = acc
// MODE 1: out += acc;      nxt = acc
// MODE 2: out += acc                (final layer, no nxt)
template <int MODE>
__global__ void k_gather(const int2* __restrict__ edges, const int* __restrict__ rowptr,
                         const int* __restrict__ counts, const float* __restrict__ x,
                         const float* __restrict__ emb, float* __restrict__ nxt,
                         float* __restrict__ out) {
    int r = blockIdx.x * (blockDim.x >> 6) + (threadIdx.x >> 6);
    if (r >= NU) return;
    int lane = threadIdx.x & 63;
    int start = rowptr[r];
    int len = counts[r];
    float acc = 0.f;
    for (int i = 0; i < len; ++i) {
        int2 ed = edges[start + i];
        acc += __int_as_float(ed.y) * x[(long long)ed.x * D + lane];
    }
    long long o = (long long)r * D + lane;
    if (MODE == 0) out[o] = emb[o] + acc;
    else           out[o] += acc;
    if (MODE != 2) nxt[o] = acc;
}

extern "C" void kernel_launch(void* const* d_in, const int* in_sizes, int n_in,
                              void* d_out, int out_size, void* d_ws, size_t ws_size,
                              hipStream_t stream) {
    const int*   rows = (const int*)d_in[0];
    const int*   cols = (const int*)d_in[1];
    const float* vals = (const float*)d_in[2];
    const float* emb  = (const float*)d_in[3];
    float* out = (float*)d_out;

    // workspace layout
    float* bufA   = (float*)d_ws;              // NU*D floats (25.6 MB)
    float* bufB   = bufA + (size_t)NU * D;     // NU*D floats (25.6 MB)
    int2*  edges  = (int2*)(bufB + (size_t)NU * D);  // NE int2 (12.8 MB)
    int*   rowptr = (int*)(edges + NE);        // NU
    int*   counts = rowptr + NU;               // NU
    int*   cursor = counts + NU;               // NU
    int*   bsums  = cursor + NU;               // 128
    int*   boff   = bsums + 128;               // 128

    const int blk = 256;

    // --- build CSR (counting sort by row) ---
    k_zero_i<<<(NU + blk - 1) / blk, blk, 0, stream>>>(counts, NU);
    k_hist<<<(NE + blk - 1) / blk, blk, 0, stream>>>(rows, counts);
    k_scan1<<<NB_SCAN, SCAN_CHUNK, 0, stream>>>(counts, rowptr, bsums);
    k_scan2<<<1, 128, 0, stream>>>(bsums, boff);
    k_scan3<<<(NU + blk - 1) / blk, blk, 0, stream>>>(rowptr, boff, cursor);
    k_scatter<<<(NE + blk - 1) / blk, blk, 0, stream>>>(rows, cols, vals, cursor, edges);

    // --- 3 gather-SpMM layers, out-accumulation fused ---
    const int rows_per_blk = blk / 64;                       // 4
    const int gG = (NU + rows_per_blk - 1) / rows_per_blk;   // 25000
    k_gather<0><<<gG, blk, 0, stream>>>(edges, rowptr, counts, emb,  emb, bufA, out);
    k_gather<1><<<gG, blk, 0, stream>>>(edges, rowptr, counts, bufA, emb, bufB, out);
    k_gather<2><<<gG, blk, 0, stream>>>(edges, rowptr, counts, bufB, emb, bufA, out);
}

// Round 3
// 393.050 us; speedup vs baseline: 2.8459x; 1.6913x over previous
//
#include <hip/hip_runtime.h>

#define NU 100000
#define D  64
#define NE 1600000

#define SCAN_CHUNK 1024
#define NB_SCAN ((NU + SCAN_CHUNK - 1) / SCAN_CHUNK)   // 98

__global__ void k_zero_i(int* __restrict__ p, int n) {
    int i = blockIdx.x * blockDim.x + threadIdx.x;
    if (i < n) p[i] = 0;
}

__global__ void k_hist(const int* __restrict__ rows, int* __restrict__ counts) {
    int e = blockIdx.x * blockDim.x + threadIdx.x;
    if (e < NE) atomicAdd(&counts[rows[e]], 1);
}

// per-block exclusive scan; writes per-block-exclusive values + block totals
__global__ void k_scan1(const int* __restrict__ counts, int* __restrict__ excl,
                        int* __restrict__ blockSums) {
    __shared__ int s[SCAN_CHUNK];
    int t = threadIdx.x;
    int idx = blockIdx.x * SCAN_CHUNK + t;
    int v = (idx < NU) ? counts[idx] : 0;
    s[t] = v;
    __syncthreads();
    for (int off = 1; off < SCAN_CHUNK; off <<= 1) {
        int x = (t >= off) ? s[t - off] : 0;
        __syncthreads();
        s[t] += x;
        __syncthreads();
    }
    if (idx < NU) excl[idx] = s[t] - v;
    if (t == SCAN_CHUNK - 1) blockSums[blockIdx.x] = s[t];
}

// single-block exclusive scan of the 98 block totals (padded to 128)
__global__ void k_scan2(const int* __restrict__ blockSums, int* __restrict__ blockOff) {
    __shared__ int s[128];
    int t = threadIdx.x;
    int v = (t < NB_SCAN) ? blockSums[t] : 0;
    s[t] = v;
    __syncthreads();
    for (int off = 1; off < 128; off <<= 1) {
        int x = (t >= off) ? s[t - off] : 0;
        __syncthreads();
        s[t] += x;
        __syncthreads();
    }
    blockOff[t] = s[t] - v;
}

__global__ void k_scan3(int* __restrict__ rowptr, const int* __restrict__ blockOff,
                        int* __restrict__ cursor) {
    int idx = blockIdx.x * blockDim.x + threadIdx.x;
    if (idx < NU) {
        int v = rowptr[idx] + blockOff[idx / SCAN_CHUNK];
        rowptr[idx] = v;
        cursor[idx] = v;
    }
}

// counting-sort edges into CSR slots: (col, val) interleaved as int2.
// After this kernel, cursor[r] == rowptr[r] + count[r] == row end.
__global__ void k_scatter(const int* __restrict__ rows, const int* __restrict__ cols,
                          const float* __restrict__ vals, int* __restrict__ cursor,
                          int2* __restrict__ edges) {
    int e = blockIdx.x * blockDim.x + threadIdx.x;
    if (e < NE) {
        int r = rows[e];
        int pos = atomicAdd(&cursor[r], 1);
        edges[pos] = make_int2(cols[e], __float_as_int(vals[e]));
    }
}

// One 64-lane wave per output row; lane = latent dim.
// Edges preloaded lane-parallel, broadcast via shfl; 4 independent
// accumulators give 4 x-row gathers in flight (latency hiding).
// MODE 0: out = emb + acc; nxt = acc
// MODE 1: out += acc;      nxt = acc
// MODE 2: out += acc                (final layer, no nxt)
template <int MODE>
__global__ void k_gather(const int2* __restrict__ edges, const int* __restrict__ rowptr,
                         const int* __restrict__ rowend, const float* __restrict__ x,
                         const float* __restrict__ emb, float* __restrict__ nxt,
                         float* __restrict__ out) {
    int r = blockIdx.x * (blockDim.x >> 6) + (threadIdx.x >> 6);
    if (r >= NU) return;
    int lane = threadIdx.x & 63;
    int start = rowptr[r];
    int end   = rowend[r];
    int len   = end - start;
    int n0 = len < 64 ? len : 64;

    int2 my = make_int2(0, 0);
    if (lane < n0) my = edges[start + lane];

    float acc0 = 0.f, acc1 = 0.f, acc2 = 0.f, acc3 = 0.f;
    int i = 0;
    for (; i + 4 <= n0; i += 4) {
        int   c0 = __shfl(my.x, i,     64);
        int   c1 = __shfl(my.x, i + 1, 64);
        int   c2 = __shfl(my.x, i + 2, 64);
        int   c3 = __shfl(my.x, i + 3, 64);
        float v0 = __int_as_float(__shfl(my.y, i,     64));
        float v1 = __int_as_float(__shfl(my.y, i + 1, 64));
        float v2 = __int_as_float(__shfl(my.y, i + 2, 64));
        float v3 = __int_as_float(__shfl(my.y, i + 3, 64));
        acc0 += v0 * x[(size_t)c0 * D + lane];
        acc1 += v1 * x[(size_t)c1 * D + lane];
        acc2 += v2 * x[(size_t)c2 * D + lane];
        acc3 += v3 * x[(size_t)c3 * D + lane];
    }
    for (; i < n0; ++i) {
        int   c = __shfl(my.x, i, 64);
        float v = __int_as_float(__shfl(my.y, i, 64));
        acc0 += v * x[(size_t)c * D + lane];
    }
    // safety: rows longer than 64 edges (essentially never at E/U=16)
    for (int j = start + 64; j < end; ++j) {
        int2 ed = edges[j];
        acc0 += __int_as_float(ed.y) * x[(size_t)ed.x * D + lane];
    }

    float acc = (acc0 + acc1) + (acc2 + acc3);
    size_t o = (size_t)r * D + lane;
    if (MODE == 0) out[o] = emb[o] + acc;
    else           out[o] += acc;
    if (MODE != 2) nxt[o] = acc;
}

extern "C" void kernel_launch(void* const* d_in, const int* in_sizes, int n_in,
                              void* d_out, int out_size, void* d_ws, size_t ws_size,
                              hipStream_t stream) {
    const int*   rows = (const int*)d_in[0];
    const int*   cols = (const int*)d_in[1];
    const float* vals = (const float*)d_in[2];
    const float* emb  = (const float*)d_in[3];
    float* out = (float*)d_out;

    // workspace layout
    float* bufA   = (float*)d_ws;                    // NU*D floats (25.6 MB)
    float* bufB   = bufA + (size_t)NU * D;           // NU*D floats (25.6 MB)
    int2*  edges  = (int2*)(bufB + (size_t)NU * D);  // NE int2 (12.8 MB)
    int*   rowptr = (int*)(edges + NE);              // NU
    int*   counts = rowptr + NU;                     // NU
    int*   cursor = counts + NU;                     // NU
    int*   bsums  = cursor + NU;                     // 128
    int*   boff   = bsums + 128;                     // 128

    const int blk = 256;

    // --- build CSR (counting sort by row) ---
    k_zero_i<<<(NU + blk - 1) / blk, blk, 0, stream>>>(counts, NU);
    k_hist<<<(NE + blk - 1) / blk, blk, 0, stream>>>(rows, counts);
    k_scan1<<<NB_SCAN, SCAN_CHUNK, 0, stream>>>(counts, rowptr, bsums);
    k_scan2<<<1, 128, 0, stream>>>(bsums, boff);
    k_scan3<<<(NU + blk - 1) / blk, blk, 0, stream>>>(rowptr, boff, cursor);
    k_scatter<<<(NE + blk - 1) / blk, blk, 0, stream>>>(rows, cols, vals, cursor, edges);

    // --- 3 gather-SpMM layers, out-accumulation fused ---
    const int rows_per_blk = blk / 64;                       // 4
    const int gG = (NU + rows_per_blk - 1) / rows_per_blk;   // 25000
    k_gather<0><<<gG, blk, 0, stream>>>(edges, rowptr, cursor, emb,  emb, bufA, out);
    k_gather<1><<<gG, blk, 0, stream>>>(edges, rowptr, cursor, bufA, emb, bufB, out);
    k_gather<2><<<gG, blk, 0, stream>>>(edges, rowptr, cursor, bufB, emb, bufA, out);
}